// Round 1
// baseline (145.779 us; speedup 1.0000x reference)
//
#include <hip/hip_runtime.h>
#include <hip/hip_bf16.h>
#include <cstdint>

typedef unsigned short u16;
typedef __bf16 bf16_t;
typedef __bf16 bf16x8 __attribute__((ext_vector_type(8)));
typedef float f32x4 __attribute__((ext_vector_type(4)));

#define DM   512
#define DFF  2048
#define NEXP 8

__device__ __forceinline__ u16 f2bf(float f) {
  bf16_t b = (bf16_t)f;
  return __builtin_bit_cast(u16, b);
}
__device__ __forceinline__ uint32_t pack_bf2(float lo, float hi) {
  return (uint32_t)f2bf(lo) | ((uint32_t)f2bf(hi) << 16);
}
__device__ __forceinline__ float gelu_tanh(float x) {
  float x3 = x * x * x;
  float z = 0.7978845608028654f * (x + 0.044715f * x3);
  float az = fabsf(z);
  float e = __expf(2.0f * az);
  float t = 1.0f - 2.0f / (e + 1.0f);
  t = copysignf(t, z);
  return 0.5f * x * (1.0f + t);
}
__device__ __forceinline__ void async16(const u16* g, u16* l) {
  __builtin_amdgcn_global_load_lds((const __attribute__((address_space(1))) void*)g,
                                   (__attribute__((address_space(3))) void*)l, 16, 0, 0);
}

// ---------- transpose + f32->bf16 convert: src [E][R][C] f32 -> dst [E][C][R] bf16
__global__ void k_transpose_cvt(const float* __restrict__ src, u16* __restrict__ dst,
                                int R, int C) {
  __shared__ u16 tile[64][65];
  int e = blockIdx.y;
  int tilesC = C >> 6;
  int bR = (blockIdx.x / tilesC) << 6;
  int bC = (blockIdx.x % tilesC) << 6;
  const float* s = src + (size_t)e * R * C;
  u16* d = dst + (size_t)e * R * C;
  int lr = threadIdx.x >> 6;   // 0..3
  int lc = threadIdx.x & 63;
#pragma unroll
  for (int i = 0; i < 16; ++i) {
    int r = (i << 2) + lr;
    tile[r][lc] = f2bf(s[(size_t)(bR + r) * C + bC + lc]);
  }
  __syncthreads();
#pragma unroll
  for (int i = 0; i < 16; ++i) {
    int c = (i << 2) + lr;
    d[(size_t)(bC + c) * R + bR + lc] = tile[lc][c];
  }
}

// ---------- router: one wave per token
__global__ void k_router(const float* __restrict__ x, const float* __restrict__ Wr,
                         const float* __restrict__ br, int* __restrict__ sel_idx,
                         float* __restrict__ sel_w, int Ntok) {
  int wid = threadIdx.x >> 6;
  int lane = threadIdx.x & 63;
  int tok = (blockIdx.x << 2) + wid;
  if (tok >= Ntok) return;
  const float4* xr = (const float4*)(x + (size_t)tok * DM);
  float4 x0 = xr[lane * 2], x1 = xr[lane * 2 + 1];
  float logit[NEXP];
#pragma unroll
  for (int e = 0; e < NEXP; ++e) {
    const float4* wr = (const float4*)(Wr + e * DM);
    float4 w0 = wr[lane * 2], w1 = wr[lane * 2 + 1];
    float p = x0.x * w0.x + x0.y * w0.y + x0.z * w0.z + x0.w * w0.w
            + x1.x * w1.x + x1.y * w1.y + x1.z * w1.z + x1.w * w1.w;
#pragma unroll
    for (int off = 32; off; off >>= 1) p += __shfl_xor(p, off, 64);
    logit[e] = p + br[e];
  }
  if (lane == 0) {
    float mx = logit[0];
#pragma unroll
    for (int e = 1; e < NEXP; ++e) mx = fmaxf(mx, logit[e]);
    float pr[NEXP];
#pragma unroll
    for (int e = 0; e < NEXP; ++e) pr[e] = __expf(logit[e] - mx);
    int i0 = 0;
#pragma unroll
    for (int e = 1; e < NEXP; ++e) if (pr[e] > pr[i0]) i0 = e;
    int i1 = -1;
#pragma unroll
    for (int e = 0; e < NEXP; ++e) {
      if (e == i0) continue;
      if (i1 < 0 || pr[e] > pr[i1]) i1 = e;
    }
    float s2 = pr[i0] + pr[i1];
    sel_idx[tok * 2]     = i0;
    sel_idx[tok * 2 + 1] = i1;
    sel_w[tok * 2]       = pr[i0] / s2;
    sel_w[tok * 2 + 1]   = pr[i1] / s2;
  }
}

// ---------- scatter: histogram + offsets + tile map + position assignment (1 block)
__global__ void k_scatter(const int* __restrict__ sel_idx, const float* __restrict__ sel_w,
                          int npairs, int* __restrict__ row_token, float* __restrict__ row_w,
                          int* __restrict__ pos_of, int* __restrict__ tileMeta,
                          int* __restrict__ gMeta) {
  __shared__ int cnt[NEXP], offs[NEXP], cur[NEXP];
  int tid = threadIdx.x;
  if (tid < NEXP) cnt[tid] = 0;
  __syncthreads();
  for (int p = tid; p < npairs; p += blockDim.x) atomicAdd(&cnt[sel_idx[p]], 1);
  __syncthreads();
  if (tid == 0) {
    int o = 0, nmt = 0;
    for (int e = 0; e < NEXP; ++e) {
      offs[e] = o;
      int c = cnt[e];
      int nt = (c + 127) >> 7;
      for (int t = 0; t < nt; ++t) {
        tileMeta[nmt * 3 + 0] = o + t * 128;  // posStart
        tileMeta[nmt * 3 + 1] = o + c;        // segEnd
        tileMeta[nmt * 3 + 2] = e;            // expert
        ++nmt;
      }
      o += c;
    }
    gMeta[0] = nmt;
  }
  if (tid < NEXP) cur[tid] = 0;
  __syncthreads();
  for (int p = tid; p < npairs; p += blockDim.x) {
    int e = sel_idx[p];
    int pos = offs[e] + atomicAdd(&cur[e], 1);
    row_token[pos] = p >> 1;
    row_w[pos] = sel_w[p];
    pos_of[p] = pos;
  }
}

// ---------- gather selected token rows -> bf16
__global__ void k_gather(const float* __restrict__ x, const int* __restrict__ row_token,
                         u16* __restrict__ Xg, int npairs) {
  int pos = (blockIdx.x << 2) + (threadIdx.x >> 6);
  int lane = threadIdx.x & 63;
  if (pos >= npairs) return;
  int tok = row_token[pos];
  const float4* src = (const float4*)(x + (size_t)tok * DM);
  float4 a = src[lane * 2], b = src[lane * 2 + 1];
  uint4 o;
  o.x = pack_bf2(a.x, a.y);
  o.y = pack_bf2(a.z, a.w);
  o.z = pack_bf2(b.x, b.y);
  o.w = pack_bf2(b.z, b.w);
  ((uint4*)(Xg + (size_t)pos * DM))[lane] = o;
}

// ---------- grouped GEMM: C[m][n] = act(A[m][:] . BT[n][:] + bias) (*w)
// A: [npairs][K] bf16   BT: [E][NFULL][K] bf16   out: bf16 [.][NFULL] or f32
template <int NFULL, int K, bool GELU, bool SCALE, bool OUTBF16>
__launch_bounds__(256)
__global__ void k_gemm(const u16* __restrict__ A, const u16* __restrict__ BT,
                       const float* __restrict__ bias, const float* __restrict__ row_w,
                       void* __restrict__ Out, const int* __restrict__ tileMeta,
                       const int* __restrict__ gMeta) {
  int mt = blockIdx.x;
  if (mt >= gMeta[0]) return;
  int nt = blockIdx.y;
  int posStart = tileMeta[mt * 3 + 0];
  int segEnd   = tileMeta[mt * 3 + 1];
  int e        = tileMeta[mt * 3 + 2];

  __shared__ u16 As[128 * 64];
  __shared__ u16 Bs[128 * 64];

  int tid = threadIdx.x;
  int lane = tid & 63, wid = tid >> 6;
  int wm = wid >> 1, wn = wid & 1;

  const u16* Bex = BT + ((size_t)e * NFULL + (size_t)nt * 128) * K;

  // staging source pointers (pre-swizzled global source, linear LDS dest)
  int sRow = (wid << 3) + (lane >> 3);   // +i*32
  int chunkDst = lane & 7;
  const u16* aSrc[4];
  const u16* bSrc[4];
#pragma unroll
  for (int i = 0; i < 4; ++i) {
    int r = (i << 5) + sRow;
    int gra = posStart + r;
    if (gra >= segEnd) gra = segEnd - 1;
    int cs = chunkDst ^ (r & 7);
    aSrc[i] = A + (size_t)gra * K + cs * 8;
    bSrc[i] = Bex + (size_t)r * K + cs * 8;
  }

  f32x4 acc[4][4] = {};
  const char* AsB = (const char*)As;
  const char* BsB = (const char*)Bs;

  for (int kt = 0; kt < K / 64; ++kt) {
    __syncthreads();
#pragma unroll
    for (int i = 0; i < 4; ++i) {
      async16(aSrc[i] + kt * 64, As + (i << 11) + (wid << 9));
      async16(bSrc[i] + kt * 64, Bs + (i << 11) + (wid << 9));
    }
    __syncthreads();
#pragma unroll
    for (int ks = 0; ks < 2; ++ks) {
      int kByte = (ks << 6) + ((lane >> 4) << 4);
      bf16x8 av[4], bv[4];
#pragma unroll
      for (int mi = 0; mi < 4; ++mi) {
        int row = (wm << 6) + (mi << 4) + (lane & 15);
        av[mi] = *(const bf16x8*)(AsB + row * 128 + (kByte ^ ((row & 7) << 4)));
      }
#pragma unroll
      for (int ni = 0; ni < 4; ++ni) {
        int row = (wn << 6) + (ni << 4) + (lane & 15);
        bv[ni] = *(const bf16x8*)(BsB + row * 128 + (kByte ^ ((row & 7) << 4)));
      }
#pragma unroll
      for (int mi = 0; mi < 4; ++mi)
#pragma unroll
        for (int ni = 0; ni < 4; ++ni)
          acc[mi][ni] = __builtin_amdgcn_mfma_f32_16x16x32_bf16(av[mi], bv[ni], acc[mi][ni], 0, 0, 0);
    }
  }

  // epilogue
  int laneCol = lane & 15;
  int laneRow4 = (lane >> 4) << 2;
  const float* biasE = bias + (size_t)e * NFULL;
#pragma unroll
  for (int mi = 0; mi < 4; ++mi) {
#pragma unroll
    for (int j = 0; j < 4; ++j) {
      int m = posStart + (wm << 6) + (mi << 4) + laneRow4 + j;
      if (m < segEnd) {
        float w = 1.0f;
        if constexpr (SCALE) w = row_w[m];
#pragma unroll
        for (int ni = 0; ni < 4; ++ni) {
          int n = (nt << 7) + (wn << 6) + (ni << 4) + laneCol;
          float v = acc[mi][ni][j] + biasE[n];
          if constexpr (GELU) v = gelu_tanh(v);
          if constexpr (SCALE) v *= w;
          if constexpr (OUTBF16)
            ((u16*)Out)[(size_t)m * NFULL + n] = f2bf(v);
          else
            ((float*)Out)[(size_t)m * NFULL + n] = v;
        }
      }
    }
  }
}

// ---------- combine: out[tok] = Ys[pos0] + Ys[pos1]   (w and b2 already applied)
__global__ void k_combine(const float* __restrict__ Ys, const int* __restrict__ pos_of,
                          float* __restrict__ out, int Ntok) {
  int tok = (blockIdx.x << 1) + (threadIdx.x >> 7);
  int t = threadIdx.x & 127;
  if (tok >= Ntok) return;
  int p0 = pos_of[tok * 2], p1 = pos_of[tok * 2 + 1];
  const float4* y0 = (const float4*)(Ys + (size_t)p0 * DM);
  const float4* y1 = (const float4*)(Ys + (size_t)p1 * DM);
  float4* o = (float4*)(out + (size_t)tok * DM);
  float4 a = y0[t], b = y1[t];
  o[t] = make_float4(a.x + b.x, a.y + b.y, a.z + b.z, a.w + b.w);
}

extern "C" void kernel_launch(void* const* d_in, const int* in_sizes, int n_in,
                              void* d_out, int out_size, void* d_ws, size_t ws_size,
                              hipStream_t stream) {
  const float* x  = (const float*)d_in[0];
  const float* Wr = (const float*)d_in[1];
  const float* br = (const float*)d_in[2];
  const float* W1 = (const float*)d_in[3];
  const float* b1 = (const float*)d_in[4];
  const float* W2 = (const float*)d_in[5];
  const float* b2 = (const float*)d_in[6];
  float* out = (float*)d_out;

  int Ntok = in_sizes[0] / DM;   // 4096
  int npairs = Ntok * 2;         // 8192
  int maxmt = npairs / 128 + NEXP;

  char* p = (char*)d_ws;
  u16* W1T = (u16*)p;  p += (size_t)NEXP * DFF * DM * 2;
  u16* W2T = (u16*)p;  p += (size_t)NEXP * DM * DFF * 2;
  u16* Xg  = (u16*)p;  p += (size_t)npairs * DM * 2;
  u16* H   = (u16*)p;  p += (size_t)npairs * DFF * 2;
  float* Ys = (float*)p; p += (size_t)npairs * DM * 4;
  int* sel_idx   = (int*)p;   p += (size_t)npairs * 4;
  float* sel_w   = (float*)p; p += (size_t)npairs * 4;
  int* pos_of    = (int*)p;   p += (size_t)npairs * 4;
  int* row_token = (int*)p;   p += (size_t)npairs * 4;
  float* row_w   = (float*)p; p += (size_t)npairs * 4;
  int* tileMeta  = (int*)p;   p += (size_t)(maxmt * 3 + 16) * 4;
  int* gMeta     = (int*)p;   p += 64;

  k_transpose_cvt<<<dim3((DM / 64) * (DFF / 64), NEXP), 256, 0, stream>>>(W1, W1T, DM, DFF);
  k_transpose_cvt<<<dim3((DFF / 64) * (DM / 64), NEXP), 256, 0, stream>>>(W2, W2T, DFF, DM);
  k_router<<<dim3((Ntok + 3) / 4), 256, 0, stream>>>(x, Wr, br, sel_idx, sel_w, Ntok);
  k_scatter<<<dim3(1), 1024, 0, stream>>>(sel_idx, sel_w, npairs, row_token, row_w,
                                          pos_of, tileMeta, gMeta);
  k_gather<<<dim3(npairs / 4), 256, 0, stream>>>(x, row_token, Xg, npairs);
  k_gemm<DFF, DM, true, false, true>
      <<<dim3(maxmt, DFF / 128), 256, 0, stream>>>(Xg, W1T, b1, nullptr, H, tileMeta, gMeta);
  k_gemm<DM, DFF, false, true, false>
      <<<dim3(maxmt, DM / 128), 256, 0, stream>>>(H, W2T, b2, row_w, Ys, tileMeta, gMeta);
  k_combine<<<dim3(Ntok / 2), 256, 0, stream>>>(Ys, pos_of, out, Ntok);
}